// Round 1
// baseline (99.150 us; speedup 1.0000x reference)
//
#include <hip/hip_runtime.h>

// Voxelizer: splat N gaussians into a D*H*W f32 volume.
// Round 6: exact ellipse ranges instead of AABB-box visits.
//   - mahal(d1,d2) = A*d2^2 + 2*(b0+b1*d1)*d2 + (c00 + 2*cy1*d1 + cyy*d1^2)
//     for a fixed z-plane. Schur complement in y gives the exact y-interval
//     (min over continuous x <= 9); per row the x-quadratic gives the exact
//     x-interval. Ranges are solved for mahal <= 9.001 with +-0.125 voxel
//     integer slack, so they strictly contain every site the inner (exact,
//     unchanged-fp) mahal<=9.0f test can accept -> bitwise-same output sites
//     as R5, ~3x fewer inner-loop iterations (~3M box visits -> ~1M).
//   - 4 threads/point (z-span of the mahal<=9 ellipsoid is < 3.87 voxels ->
//     at most 4 integer planes), planes from ceil(c0-h0): contiguous active
//     lanes instead of 5/point with ~40% idle.

#define VOX_D 128
#define VOX_H 128
#define VOX_W 128
#define TPP 4   // threads (z-planes) per point

__global__ __launch_bounds__(256) void voxelize_splat(
    const float* __restrict__ positions,  // (N,3)
    const float* __restrict__ scales,     // (N,3)
    const float* __restrict__ rotations,  // (N,4) w,x,y,z
    const float* __restrict__ density,    // (N,)
    float* __restrict__ volume,           // (D*H*W,)
    int n)
{
    const int tid = blockIdx.x * blockDim.x + threadIdx.x;
    if (tid >= n * TPP) return;
    const int i = tid >> 2;               // point index
    const int t = tid & 3;                // plane slot 0..3

    const float p0 = positions[3 * i + 0];
    const float p1 = positions[3 * i + 1];
    const float p2 = positions[3 * i + 2];

    // voxel-space center (all dims are 128)
    const float c0 = (p0 + 1.0f) * 64.0f - 0.5f;
    const float c1 = (p1 + 1.0f) * 64.0f - 0.5f;
    const float c2 = (p2 + 1.0f) * 64.0f - 0.5f;

    // quaternion -> rotation matrix (normalized)
    float qw = rotations[4 * i + 0];
    float qx = rotations[4 * i + 1];
    float qy = rotations[4 * i + 2];
    float qz = rotations[4 * i + 3];
    const float qn = rsqrtf(qw * qw + qx * qx + qy * qy + qz * qz);
    qw *= qn; qx *= qn; qy *= qn; qz *= qn;

    const float r00 = 1.0f - 2.0f * (qy * qy + qz * qz);
    const float r01 = 2.0f * (qx * qy - qw * qz);
    const float r02 = 2.0f * (qx * qz + qw * qy);
    const float r10 = 2.0f * (qx * qy + qw * qz);
    const float r11 = 1.0f - 2.0f * (qx * qx + qz * qz);
    const float r12 = 2.0f * (qy * qz - qw * qx);
    const float r20 = 2.0f * (qx * qz - qw * qy);
    const float r21 = 2.0f * (qy * qz + qw * qx);
    const float r22 = 1.0f - 2.0f * (qx * qx + qy * qy);

    const float s0 = scales[3 * i + 0];
    const float s1 = scales[3 * i + 1];
    const float s2 = scales[3 * i + 2];

    // exact z half-extent of the mahal<=9 ellipsoid (support function), +eps
    const float h0 = 192.0f * sqrtf(r00 * r00 * s0 * s0 + r01 * r01 * s1 * s1
                                    + r02 * r02 * s2 * s2) + 1e-2f;

    int zlo = (int)ceilf(c0 - h0);
    if (zlo < 0) zlo = 0;
    const int g0 = zlo + t;               // this thread's plane
    if ((float)g0 > c0 + h0 || g0 >= VOX_D) return;

    const float si0 = 1.0f / (s0 + 1e-8f);
    const float si1 = 1.0f / (s1 + 1e-8f);
    const float si2 = 1.0f / (s2 + 1e-8f);
    const float inv_half = 0.015625f;     // 1/64

    const float d0 = ((float)g0 - c0) * inv_half;

    // fixed plane terms (same expressions as R5's inner math)
    const float a0 = r00 * d0;
    const float a1 = r01 * d0;
    const float a2 = r02 * d0;

    // quadratic-form coefficients, w_j = si_j^2
    const float w0 = si0 * si0, w1 = si1 * si1, w2 = si2 * si2;
    const float A   = w0 * r20 * r20 + w1 * r21 * r21 + w2 * r22 * r22;
    const float b0c = w0 * r20 * a0  + w1 * r21 * a1  + w2 * r22 * a2;
    const float b1c = w0 * r20 * r10 + w1 * r21 * r11 + w2 * r22 * r12;
    const float cyy = w0 * r10 * r10 + w1 * r11 * r11 + w2 * r12 * r12;
    const float cy1 = w0 * r10 * a0  + w1 * r11 * a1  + w2 * r12 * a2;
    const float c00 = w0 * a0 * a0   + w1 * a1 * a1   + w2 * a2 * a2;

    const float invA = 1.0f / A;          // A >= si_min^2 ~ 1e4 > 0 always

    // Schur complement in y: min over continuous x of mahal <= 9.001
    const float S2 = cyy - b1c * b1c * invA;
    const float S1 = cy1 - b0c * b1c * invA;
    const float S0 = c00 - b0c * b0c * invA - 9.001f;

    float d1lo, d1hi;
    if (S2 > 0.0f) {                      // PD => always, guarded anyway
        const float discy = S1 * S1 - S2 * S0;
        if (!(discy > 0.0f)) return;      // plane outside ellipsoid
        const float sq = sqrtf(discy);
        const float invS2 = 1.0f / S2;
        d1lo = (-S1 - sq) * invS2;
        d1hi = (-S1 + sq) * invS2;
    } else {                              // degenerate fp fallback: full AABB
        d1lo = -0.0325f; d1hi = 0.0325f;  // +-2.08 voxels in d-units
    }

    const float EPS = 0.125f;             // integer-conversion slack (voxels)
    int lo1 = (int)ceilf (c1 + 64.0f * d1lo - EPS); if (lo1 < 0) lo1 = 0;
    int hi1 = (int)floorf(c1 + 64.0f * d1hi + EPS); if (hi1 > VOX_H - 1) hi1 = VOX_H - 1;
    if (lo1 > hi1) return;

    const float dens = density[i];
    const int plane_base = g0 * (VOX_H * VOX_W);

    for (int g1 = lo1; g1 <= hi1; ++g1) {
        const float d1 = ((float)g1 - c1) * inv_half;

        // exact x-interval for this row: A*d2^2 + 2*Bh*d2 + Cq <= 0
        const float Bh = b0c + b1c * d1;
        const float Cq = c00 + (2.0f * cy1 + cyy * d1) * d1 - 9.001f;
        const float discx = Bh * Bh - A * Cq;
        if (!(discx > 0.0f)) continue;    // row misses the ellipse
        const float sqx = sqrtf(discx);
        const float d2lo = (-Bh - sqx) * invA;
        const float d2hi = (-Bh + sqx) * invA;
        int lo2 = (int)ceilf (c2 + 64.0f * d2lo - EPS); if (lo2 < 0) lo2 = 0;
        int hi2 = (int)floorf(c2 + 64.0f * d2hi + EPS); if (hi2 > VOX_W - 1) hi2 = VOX_W - 1;
        if (lo2 > hi2) continue;

        // R5's inner math, fp-identical: decides inclusion and value
        const float e0 = a0 + r10 * d1;
        const float e1 = a1 + r11 * d1;
        const float e2 = a2 + r12 * d1;
        const int row_base = plane_base + g1 * VOX_W;
        for (int g2 = lo2; g2 <= hi2; ++g2) {
            const float d2 = ((float)g2 - c2) * inv_half;
            const float m0 = si0 * (e0 + r20 * d2);
            const float m1 = si1 * (e1 + r21 * d2);
            const float m2 = si2 * (e2 + r22 * d2);
            const float mahal = m0 * m0 + m1 * m1 + m2 * m2;
            if (mahal <= 9.0f) {
                const float val = __expf(-0.5f * mahal) * dens;
                atomicAdd(&volume[row_base + g2], val);
            }
        }
    }
}

extern "C" void kernel_launch(void* const* d_in, const int* in_sizes, int n_in,
                              void* d_out, int out_size, void* d_ws, size_t ws_size,
                              hipStream_t stream) {
    const float* positions = (const float*)d_in[0];
    const float* scales    = (const float*)d_in[1];
    const float* rotations = (const float*)d_in[2];
    const float* density   = (const float*)d_in[3];
    float* volume = (float*)d_out;

    const int n = in_sizes[0] / 3;

    // harness poisons d_out with 0xAA before every launch; we need zeros
    hipMemsetAsync(volume, 0, (size_t)out_size * sizeof(float), stream);

    const int block = 256;
    const int total = n * TPP;            // one thread per (point, plane-slot)
    const int grid = (total + block - 1) / block;
    voxelize_splat<<<grid, block, 0, stream>>>(positions, scales, rotations,
                                               density, volume, n);
}